// Round 1
// baseline (362.772 us; speedup 1.0000x reference)
//
#include <hip/hip_runtime.h>
#include <math.h>

// Problem constants (from setup_inputs / reference)
#define CLASSES   5
#define C_DIM     64
#define HW        441            // 21*21
#define B_ANCH    32
#define NSUP      25             // L*S support images
#define NROWS     (B_ANCH*HW)    // 14112 query rows
#define MSUP      (NSUP*HW)      // 11025 support descriptors
#define PER_CLS   (MSUP/CLASSES) // 2205
#define NCHUNK    5
#define CHUNK_SZ  (PER_CLS/NCHUNK) // 441

#define NEG_INF  (-1e30f)

// ---------------------------------------------------------------------------
// Kernel 1: normalize support descriptors into s_ws[m][c] (row-major, C inner)
// One wave per descriptor m; lane = channel c.
// support layout: (j, c, p) -> j*C_DIM*HW + c*HW + p ; m = j*HW + p
// ---------------------------------------------------------------------------
__global__ __launch_bounds__(256) void norm_support_kernel(
    const float* __restrict__ sup, float* __restrict__ s_ws) {
    int gtid = blockIdx.x * blockDim.x + threadIdx.x;
    int wave = gtid >> 6;
    int lane = threadIdx.x & 63;
    bool valid = wave < MSUP;
    int m = valid ? wave : (MSUP - 1);
    int j = m / HW;
    int p = m % HW;
    float v = sup[j * C_DIM * HW + lane * HW + p];
    float ss = v * v;
    #pragma unroll
    for (int off = 32; off; off >>= 1) ss += __shfl_xor(ss, off, 64);
    float scale = rsqrtf(ss);
    if (valid) s_ws[m * C_DIM + lane] = v * scale;
}

// ---------------------------------------------------------------------------
// Kernel 2: per (query row, class, chunk) partial top-3 of raw dot products.
// Lane-per-row mapping: each thread owns one query row; the 64 channels of
// its (unnormalized) query vector live in VGPRs. Support rows are read with
// wave-uniform addresses (scalar loads). Query L2-norm is deferred: we select
// top-3 on unscaled dots (scale > 0, monotone) and scale at the write.
// part layout: [row][class][chunk][3]
// ---------------------------------------------------------------------------
__global__ __launch_bounds__(256) void knn_partial_kernel(
    const float* __restrict__ anchor, const float* __restrict__ s_ws,
    float* __restrict__ part) {
    int rowRaw = blockIdx.x * 256 + threadIdx.x;
    bool valid = rowRaw < NROWS;
    int row = valid ? rowRaw : (NROWS - 1);
    int cls = blockIdx.y;
    int chunk = blockIdx.z;
    int b = row / HW;
    int p = row % HW;

    // Load this row's query vector (strided over channels; lanes are
    // consecutive p -> coalesced per channel) and its squared norm.
    const float* abase = anchor + b * C_DIM * HW + p;
    float q[C_DIM];
    float ss = 0.f;
    #pragma unroll
    for (int c = 0; c < C_DIM; ++c) {
        q[c] = abase[c * HW];
        ss += q[c] * q[c];
    }

    const float* sbase = s_ws + (cls * PER_CLS + chunk * CHUNK_SZ) * C_DIM;

    float t0 = NEG_INF, t1 = NEG_INF, t2 = NEG_INF;
    for (int i = 0; i < CHUNK_SZ; ++i) {
        const float* sr = sbase + i * C_DIM;  // wave-uniform -> scalar loads
        float s0 = 0.f, s1 = 0.f, s2 = 0.f, s3 = 0.f;
        #pragma unroll
        for (int c = 0; c < C_DIM; c += 4) {
            s0 += q[c + 0] * sr[c + 0];
            s1 += q[c + 1] * sr[c + 1];
            s2 += q[c + 2] * sr[c + 2];
            s3 += q[c + 3] * sr[c + 3];
        }
        float sim = (s0 + s1) + (s2 + s3);
        // branchless running top-3 (t0 >= t1 >= t2)
        float lo  = fminf(sim, t0); t0 = fmaxf(sim, t0);
        float lo2 = fminf(lo,  t1); t1 = fmaxf(lo,  t1);
        t2 = fmaxf(lo2, t2);
    }

    if (valid) {
        float scale = rsqrtf(ss);   // deferred query normalization
        float* pp = part + ((row * CLASSES + cls) * NCHUNK + chunk) * 3;
        pp[0] = t0 * scale;
        pp[1] = t1 * scale;
        pp[2] = t2 * scale;
    }
}

// ---------------------------------------------------------------------------
// Kernel 3: merge the 5 partial top-3s per (row, class), sigmoid, and reduce
// over the 441 query locations. One 64-thread block per (b, l) output element;
// direct store, no atomics, no d_out pre-zeroing needed.
// ---------------------------------------------------------------------------
__global__ __launch_bounds__(64) void knn_merge_kernel(
    const float* __restrict__ part, float* __restrict__ out) {
    int bl = blockIdx.x;            // 0 .. 32*5-1
    int b = bl / CLASSES;
    int l = bl % CLASSES;
    int lane = threadIdx.x;

    float acc = 0.f;
    for (int p = lane; p < HW; p += 64) {
        int row = b * HW + p;
        const float* pp = part + ((row * CLASSES + l) * NCHUNK) * 3;
        float t0 = NEG_INF, t1 = NEG_INF, t2 = NEG_INF;
        #pragma unroll
        for (int k = 0; k < NCHUNK * 3; ++k) {
            float v = pp[k];
            float lo  = fminf(v,  t0); t0 = fmaxf(v,  t0);
            float lo2 = fminf(lo, t1); t1 = fmaxf(lo, t1);
            t2 = fmaxf(lo2, t2);
        }
        acc += 1.f / (1.f + __expf(-t0))
             + 1.f / (1.f + __expf(-t1))
             + 1.f / (1.f + __expf(-t2));
    }
    #pragma unroll
    for (int off = 32; off; off >>= 1) acc += __shfl_xor(acc, off, 64);
    if (lane == 0) out[bl] = acc;
}

// ---------------------------------------------------------------------------
extern "C" void kernel_launch(void* const* d_in, const int* in_sizes, int n_in,
                              void* d_out, int out_size, void* d_ws, size_t ws_size,
                              hipStream_t stream) {
    const float* anchor  = (const float*)d_in[0];
    const float* support = (const float*)d_in[1];
    // d_in[2] = av_num (1), d_in[3] = sav_num (1) -- fixed by setup, ignored.

    float* s_ws = (float*)d_ws;                       // MSUP*C_DIM floats (2.82 MB)
    float* part = s_ws + (size_t)MSUP * C_DIM;        // NROWS*CLASSES*NCHUNK*3 floats (4.23 MB)

    {
        int total = MSUP * 64;
        dim3 g((total + 255) / 256);
        norm_support_kernel<<<g, 256, 0, stream>>>(support, s_ws);
    }
    {
        dim3 g((NROWS + 255) / 256, CLASSES, NCHUNK);
        knn_partial_kernel<<<g, 256, 0, stream>>>(anchor, s_ws, part);
    }
    {
        dim3 g(B_ANCH * CLASSES);
        knn_merge_kernel<<<g, 64, 0, stream>>>(part, (float*)d_out);
    }
}

// Round 2
// 174.283 us; speedup vs baseline: 2.0815x; 2.0815x over previous
//
#include <hip/hip_runtime.h>
#include <hip/hip_bf16.h>
#include <math.h>

// Problem constants (from setup_inputs / reference)
#define CLASSES   5
#define C_DIM     64
#define HW        441            // 21*21
#define B_ANCH    32
#define NSUP      25             // L*S support images
#define NROWS     (B_ANCH*HW)    // 14112 query rows
#define MSUP      (NSUP*HW)      // 11025 support descriptors
#define PER_CLS   (MSUP/CLASSES) // 2205 support descriptors per class

#define NEG_INF  (-1e30f)

typedef __bf16 bf16x8 __attribute__((ext_vector_type(8)));
typedef float  f32x4  __attribute__((ext_vector_type(4)));

// branchless insert of v into sorted top-3 (t0 >= t1 >= t2)
#define TOP3_INS(v, t0, t1, t2) do {                          \
    float _lo  = fminf((v), (t0)); (t0) = fmaxf((v), (t0));   \
    float _lo2 = fminf(_lo, (t1)); (t1) = fmaxf(_lo, (t1));   \
    (t2) = fmaxf(_lo2, (t2)); } while (0)

// ---------------------------------------------------------------------------
// Kernel 1: L2-normalize descriptor rows -> row-major bf16 [row][64].
// Input layout (img, c, p): in[(img*64 + c)*441 + p];  row = img*441 + p.
// Thread-per-row: channel loads are coalesced across lanes (consecutive p).
// ---------------------------------------------------------------------------
__global__ __launch_bounds__(256) void norm_rows_kernel(
    const float* __restrict__ in, __bf16* __restrict__ out, int nrows) {
    int r = blockIdx.x * 256 + threadIdx.x;
    bool valid = r < nrows;
    int rc = valid ? r : nrows - 1;
    int img = rc / HW, p = rc % HW;
    const float* base = in + (size_t)img * C_DIM * HW + p;
    float q[C_DIM];
    float ss = 0.f;
    #pragma unroll
    for (int c = 0; c < C_DIM; ++c) { q[c] = base[c * HW]; ss += q[c] * q[c]; }
    float sc = rsqrtf(ss);
    if (!valid) return;
    __bf16* op = out + (size_t)rc * C_DIM;
    #pragma unroll
    for (int c0 = 0; c0 < C_DIM; c0 += 8) {
        bf16x8 v;
        #pragma unroll
        for (int j = 0; j < 8; ++j) v[j] = (__bf16)(q[c0 + j] * sc);
        *(bf16x8*)(op + c0) = v;
    }
}

// ---------------------------------------------------------------------------
// Kernel 2: MFMA GEMM + per-(row,class) top-3 + sigmoid.
// Grid: (ceil(NROWS/64), CLASSES). Block: 256 threads = 4 waves.
// Wave w owns query rows [blk*64 + w*16, +16). A-frags (K=64) live in VGPRs.
// Streams 16-column tiles of the class's support rows; 2x mfma_16x16x32_bf16
// per tile (zero C-in); branchless top-3 insert on the 4 accumulator lanes.
// C/D layout (verified): col = lane&15, row = (lane>>4)*4 + reg.
// A/B frag: row/col = lane&15, k = (lane>>4)*8 + [0..7] (8 contiguous bf16).
// ---------------------------------------------------------------------------
__global__ __launch_bounds__(256) void knn_mfma_kernel(
    const __bf16* __restrict__ qb, const __bf16* __restrict__ sb,
    float* __restrict__ rowcls /* [NROWS][CLASSES] */) {
    int w    = threadIdx.x >> 6;
    int lane = threadIdx.x & 63;
    int lr   = lane & 15;      // A-row / B-col / C-col index
    int kg   = lane >> 4;      // k-group
    int cls  = blockIdx.y;
    int rowbase = blockIdx.x * 64 + w * 16;

    // A fragments for this wave's 16 rows, K = 64 (two K=32 halves)
    int arow = rowbase + lr;
    int arc  = arow < NROWS ? arow : NROWS - 1;
    const bf16x8* qrow = (const bf16x8*)(qb + (size_t)arc * C_DIM);
    bf16x8 a0 = qrow[kg];       // k = kg*8 .. kg*8+7
    bf16x8 a1 = qrow[4 + kg];   // k = 32 + kg*8 ..

    float t3[4][3];
    #pragma unroll
    for (int j = 0; j < 4; ++j) {
        t3[j][0] = NEG_INF; t3[j][1] = NEG_INF; t3[j][2] = NEG_INF;
    }

    // B stream: support row = cls*PER_CLS + t*16 + lr
    const bf16x8* sp = (const bf16x8*)(sb + (size_t)(cls * PER_CLS + lr) * C_DIM) + kg;
    const int nfull = PER_CLS / 16;  // 137 full tiles
    bf16x8 b0 = sp[0], b1 = sp[4];
    for (int t = 0; t < nfull; ++t) {
        bf16x8 nb0 = sp[128], nb1 = sp[132];   // prefetch next tile (reg dbuf)
        f32x4 acc = {0.f, 0.f, 0.f, 0.f};
        acc = __builtin_amdgcn_mfma_f32_16x16x32_bf16(a0, b0, acc, 0, 0, 0);
        acc = __builtin_amdgcn_mfma_f32_16x16x32_bf16(a1, b1, acc, 0, 0, 0);
        #pragma unroll
        for (int j = 0; j < 4; ++j) {
            float v = acc[j];
            TOP3_INS(v, t3[j][0], t3[j][1], t3[j][2]);
        }
        b0 = nb0; b1 = nb1; sp += 128;
    }
    {   // tail tile: columns nfull*16 .. PER_CLS+? (mask invalid cols)
        int col  = nfull * 16 + lr;
        int colc = col < PER_CLS ? col : PER_CLS - 1;
        const bf16x8* tp = (const bf16x8*)(sb + (size_t)(cls * PER_CLS + colc) * C_DIM) + kg;
        bf16x8 tb0 = tp[0], tb1 = tp[4];
        f32x4 acc = {0.f, 0.f, 0.f, 0.f};
        acc = __builtin_amdgcn_mfma_f32_16x16x32_bf16(a0, tb0, acc, 0, 0, 0);
        acc = __builtin_amdgcn_mfma_f32_16x16x32_bf16(a1, tb1, acc, 0, 0, 0);
        float neg = col < PER_CLS ? 0.f : NEG_INF;
        #pragma unroll
        for (int j = 0; j < 4; ++j) {
            float v = acc[j] + neg;
            TOP3_INS(v, t3[j][0], t3[j][1], t3[j][2]);
        }
    }

    // Merge top-3 across the 16 lanes (columns) sharing each output row,
    // butterfly over the low 4 lane bits; then sigmoid-sum and store.
    #pragma unroll
    for (int j = 0; j < 4; ++j) {
        float u0 = t3[j][0], u1 = t3[j][1], u2 = t3[j][2];
        #pragma unroll
        for (int off = 1; off < 16; off <<= 1) {
            float v0 = __shfl_xor(u0, off, 64);
            float v1 = __shfl_xor(u1, off, 64);
            float v2 = __shfl_xor(u2, off, 64);
            TOP3_INS(v0, u0, u1, u2);
            TOP3_INS(v1, u0, u1, u2);
            TOP3_INS(v2, u0, u1, u2);
        }
        int row = rowbase + kg * 4 + j;
        if (lr == 0 && row < NROWS) {
            float s = 1.f / (1.f + __expf(-u0))
                    + 1.f / (1.f + __expf(-u1))
                    + 1.f / (1.f + __expf(-u2));
            rowcls[(size_t)row * CLASSES + cls] = s;
        }
    }
}

// ---------------------------------------------------------------------------
// Kernel 3: reduce per-(row,class) scalars over the 441 query locations.
// One 64-lane block per (b, l) output; direct store, deterministic.
// ---------------------------------------------------------------------------
__global__ __launch_bounds__(64) void reduce_kernel(
    const float* __restrict__ rowcls, float* __restrict__ out) {
    int bl = blockIdx.x;
    int b = bl / CLASSES;
    int l = bl % CLASSES;
    int lane = threadIdx.x;
    float acc = 0.f;
    for (int p = lane; p < HW; p += 64)
        acc += rowcls[(size_t)(b * HW + p) * CLASSES + l];
    #pragma unroll
    for (int off = 32; off; off >>= 1) acc += __shfl_xor(acc, off, 64);
    if (lane == 0) out[bl] = acc;
}

// ---------------------------------------------------------------------------
extern "C" void kernel_launch(void* const* d_in, const int* in_sizes, int n_in,
                              void* d_out, int out_size, void* d_ws, size_t ws_size,
                              hipStream_t stream) {
    const float* anchor  = (const float*)d_in[0];
    const float* support = (const float*)d_in[1];
    // d_in[2]=av_num(1), d_in[3]=sav_num(1) -- fixed by setup, ignored.

    // ws layout: sb (bf16 MSUP*64) | qb (bf16 NROWS*64) | rowcls (f32 NROWS*5)
    __bf16* sb = (__bf16*)d_ws;
    __bf16* qb = sb + (size_t)MSUP * C_DIM;
    float* rowcls = (float*)(qb + (size_t)NROWS * C_DIM);

    {
        dim3 g((MSUP + 255) / 256);
        norm_rows_kernel<<<g, 256, 0, stream>>>(support, sb, MSUP);
    }
    {
        dim3 g((NROWS + 255) / 256);
        norm_rows_kernel<<<g, 256, 0, stream>>>(anchor, qb, NROWS);
    }
    {
        dim3 g((NROWS + 63) / 64, CLASSES);
        knn_mfma_kernel<<<g, 256, 0, stream>>>(qb, sb, rowcls);
    }
    {
        dim3 g(B_ANCH * CLASSES);
        reduce_kernel<<<g, 64, 0, stream>>>(rowcls, (float*)d_out);
    }
}

// Round 3
// 170.601 us; speedup vs baseline: 2.1264x; 1.0216x over previous
//
#include <hip/hip_runtime.h>
#include <hip/hip_bf16.h>
#include <math.h>

// Problem constants (from setup_inputs / reference)
#define CLASSES     5
#define C_DIM       64
#define HW          441            // 21*21
#define B_ANCH      32
#define NSUP        25             // L*S support images
#define NROWS       (B_ANCH*HW)    // 14112 query rows
#define MSUP        (NSUP*HW)      // 11025 support descriptors
#define PER_CLS     (MSUP/CLASSES) // 2205 support descriptors per class
#define PER_CLS_PAD 2240           // 35 * 64 (padded; pad rows never written)

#define NEG_INF  (-1e30f)

typedef __bf16 bf16x8 __attribute__((ext_vector_type(8)));
typedef float  f32x4  __attribute__((ext_vector_type(4)));

// top-3 insert via med3: 3 independent ops (vs 5 chained min/max).
// t0 >= t1 >= t2 invariant; all three results read OLD values.
#define TOP3_INS(v, t0, t1, t2) do {                              \
    float _v = (v);                                               \
    float _n0 = fmaxf(_v, (t0));                                  \
    float _n1 = __builtin_amdgcn_fmed3f(_v, (t0), (t1));          \
    float _n2 = __builtin_amdgcn_fmed3f(_v, (t1), (t2));          \
    (t0) = _n0; (t1) = _n1; (t2) = _n2; } while (0)

// ---------------------------------------------------------------------------
// Kernel 1: L2-normalize all descriptor rows (support then anchor) into
// row-major bf16. Support goes to sb with per-class row stride PER_CLS_PAD.
// Input layout (img, c, p): in[(img*64 + c)*441 + p]; row = img*441 + p.
// Thread-per-row; channel loads coalesced across lanes (consecutive p).
// ---------------------------------------------------------------------------
__global__ __launch_bounds__(256) void norm_rows_kernel(
    const float* __restrict__ anchor, const float* __restrict__ support,
    __bf16* __restrict__ qb, __bf16* __restrict__ sb) {
    int r = blockIdx.x * 256 + threadIdx.x;
    if (r >= MSUP + NROWS) return;          // no cross-lane ops: safe early-out
    bool isSup = r < MSUP;
    int rc = isSup ? r : r - MSUP;
    const float* in = isSup ? support : anchor;
    int img = rc / HW, p = rc % HW;
    const float* base = in + (size_t)img * C_DIM * HW + p;
    float q[C_DIM];
    float ss = 0.f;
    #pragma unroll
    for (int c = 0; c < C_DIM; ++c) { q[c] = base[c * HW]; ss += q[c] * q[c]; }
    float sc = rsqrtf(ss);
    __bf16* op;
    if (isSup) {
        int cls = rc / PER_CLS, ix = rc - cls * PER_CLS;
        op = sb + ((size_t)cls * PER_CLS_PAD + ix) * C_DIM;
    } else {
        op = qb + (size_t)rc * C_DIM;
    }
    #pragma unroll
    for (int c0 = 0; c0 < C_DIM; c0 += 8) {
        bf16x8 v;
        #pragma unroll
        for (int j = 0; j < 8; ++j) v[j] = (__bf16)(q[c0 + j] * sc);
        *(bf16x8*)(op + c0) = v;
    }
}

// ---------------------------------------------------------------------------
// Kernel 2: MFMA GEMM + per-(row,class) top-3 + sigmoid.
// Grid: (ceil(NROWS/64), CLASSES). Block: 256 threads = 4 waves.
// Wave w owns 16 query rows; A-frags (K=64) in VGPRs. Streams 64-column
// tiles (8 B-frag loads, 8 MFMAs) with ping-pong register double buffer.
// A/B frag: row/col = lane&15, k = (lane>>4)*8 + [0..7].
// C/D: col(N) = lane&15, row(M) = (lane>>4)*4 + reg.   (verified round 2)
// ---------------------------------------------------------------------------
__device__ __forceinline__ void loadb(const __bf16* bbase, int t, bf16x8 f[8]) {
    const __bf16* p  = bbase + (size_t)t * (64 * C_DIM);
    const __bf16* p2 = p + 32 * C_DIM;
    f[0] = *(const bf16x8*)(p);
    f[1] = *(const bf16x8*)(p + 32);
    f[2] = *(const bf16x8*)(p + 16 * C_DIM);
    f[3] = *(const bf16x8*)(p + 16 * C_DIM + 32);
    f[4] = *(const bf16x8*)(p2);
    f[5] = *(const bf16x8*)(p2 + 32);
    f[6] = *(const bf16x8*)(p2 + 16 * C_DIM);
    f[7] = *(const bf16x8*)(p2 + 16 * C_DIM + 32);
}

__device__ __forceinline__ void compute_tile(
    const bf16x8& a0, const bf16x8& a1, const bf16x8 f[8],
    float t0[4], float t1[4], float t2[4]) {
    #pragma unroll
    for (int u = 0; u < 4; ++u) {
        f32x4 acc = {0.f, 0.f, 0.f, 0.f};
        acc = __builtin_amdgcn_mfma_f32_16x16x32_bf16(a0, f[2*u],   acc, 0, 0, 0);
        acc = __builtin_amdgcn_mfma_f32_16x16x32_bf16(a1, f[2*u+1], acc, 0, 0, 0);
        #pragma unroll
        for (int j = 0; j < 4; ++j) TOP3_INS(acc[j], t0[j], t1[j], t2[j]);
    }
}

__global__ __launch_bounds__(256) void knn_mfma_kernel(
    const __bf16* __restrict__ qb, const __bf16* __restrict__ sb,
    float* __restrict__ rowcls /* [NROWS][CLASSES] */) {
    int lane = threadIdx.x & 63;
    int w    = threadIdx.x >> 6;
    int lr   = lane & 15;      // A-row / B-col index
    int kg   = lane >> 4;      // k-group
    int cls  = blockIdx.y;
    int rowbase = blockIdx.x * 64 + w * 16;

    // A fragments for this wave's 16 rows, K = 64 (two K=32 halves)
    int arow = rowbase + lr;
    int arc  = arow < NROWS ? arow : NROWS - 1;
    const bf16x8* qrow = (const bf16x8*)(qb + (size_t)arc * C_DIM);
    bf16x8 a0 = qrow[kg];       // k = kg*8 ..
    bf16x8 a1 = qrow[4 + kg];   // k = 32 + kg*8 ..

    float t0[4], t1[4], t2[4];
    #pragma unroll
    for (int j = 0; j < 4; ++j) { t0[j] = NEG_INF; t1[j] = NEG_INF; t2[j] = NEG_INF; }

    // B lane base: support row (cls*PAD + lr), k-offset kg*8
    const __bf16* bbase = sb + ((size_t)cls * PER_CLS_PAD + lr) * C_DIM + kg * 8;

    bf16x8 fa[8], fb[8];
    loadb(bbase, 0, fa);
    #pragma unroll 1
    for (int it = 0; it < 17; ++it) {          // tiles 0..33 computed here
        loadb(bbase, 2 * it + 1, fb);
        compute_tile(a0, a1, fa, t0, t1, t2);
        loadb(bbase, 2 * it + 2, fa);          // it=16 loads tile 34 (tail)
        compute_tile(a0, a1, fb, t0, t1, t2);
    }
    {   // tail tile 34: cols 2176 + u*16 + lr; valid iff col < 2205
        // u=0 (cols 2176..2191): all valid
        f32x4 acc = {0.f, 0.f, 0.f, 0.f};
        acc = __builtin_amdgcn_mfma_f32_16x16x32_bf16(a0, fa[0], acc, 0, 0, 0);
        acc = __builtin_amdgcn_mfma_f32_16x16x32_bf16(a1, fa[1], acc, 0, 0, 0);
        #pragma unroll
        for (int j = 0; j < 4; ++j) TOP3_INS(acc[j], t0[j], t1[j], t2[j]);
        // u=1 (cols 2192..2207): valid iff lr < 13. SELECT mask (not add):
        // pad rows are never written -> could be NaN; keep them out entirely.
        f32x4 acc2 = {0.f, 0.f, 0.f, 0.f};
        acc2 = __builtin_amdgcn_mfma_f32_16x16x32_bf16(a0, fa[2], acc2, 0, 0, 0);
        acc2 = __builtin_amdgcn_mfma_f32_16x16x32_bf16(a1, fa[3], acc2, 0, 0, 0);
        bool valid = (2192 + lr) < PER_CLS;
        #pragma unroll
        for (int j = 0; j < 4; ++j) {
            float v = valid ? acc2[j] : NEG_INF;
            TOP3_INS(v, t0[j], t1[j], t2[j]);
        }
        // u=2,3: entirely out of range -> skipped
    }

    // Merge top-3 across the 16 column-lanes per row; sigmoid; store.
    #pragma unroll
    for (int j = 0; j < 4; ++j) {
        float u0 = t0[j], u1 = t1[j], u2 = t2[j];
        #pragma unroll
        for (int off = 1; off < 16; off <<= 1) {
            float v0 = __shfl_xor(u0, off, 64);
            float v1 = __shfl_xor(u1, off, 64);
            float v2 = __shfl_xor(u2, off, 64);
            TOP3_INS(v0, u0, u1, u2);
            TOP3_INS(v1, u0, u1, u2);
            TOP3_INS(v2, u0, u1, u2);
        }
        int row = rowbase + kg * 4 + j;
        if (lr == 0 && row < NROWS) {
            float s = 1.f / (1.f + __expf(-u0))
                    + 1.f / (1.f + __expf(-u1))
                    + 1.f / (1.f + __expf(-u2));
            rowcls[(size_t)row * CLASSES + cls] = s;
        }
    }
}

// ---------------------------------------------------------------------------
// Kernel 3: reduce per-(row,class) scalars over the 441 query locations.
// One 64-lane block per (b, l) output; direct store, deterministic.
// ---------------------------------------------------------------------------
__global__ __launch_bounds__(64) void reduce_kernel(
    const float* __restrict__ rowcls, float* __restrict__ out) {
    int bl = blockIdx.x;
    int b = bl / CLASSES;
    int l = bl % CLASSES;
    int lane = threadIdx.x;
    float acc = 0.f;
    for (int p = lane; p < HW; p += 64)
        acc += rowcls[(size_t)(b * HW + p) * CLASSES + l];
    #pragma unroll
    for (int off = 32; off; off >>= 1) acc += __shfl_xor(acc, off, 64);
    if (lane == 0) out[bl] = acc;
}

// ---------------------------------------------------------------------------
extern "C" void kernel_launch(void* const* d_in, const int* in_sizes, int n_in,
                              void* d_out, int out_size, void* d_ws, size_t ws_size,
                              hipStream_t stream) {
    const float* anchor  = (const float*)d_in[0];
    const float* support = (const float*)d_in[1];
    // d_in[2]=av_num(1), d_in[3]=sav_num(1) -- fixed by setup, ignored.

    // ws layout: sb (bf16 5*PER_CLS_PAD*64) | qb (bf16 NROWS*64) | rowcls (f32)
    __bf16* sb = (__bf16*)d_ws;
    __bf16* qb = sb + (size_t)CLASSES * PER_CLS_PAD * C_DIM;
    float* rowcls = (float*)(qb + (size_t)NROWS * C_DIM);

    {
        int total = MSUP + NROWS;
        dim3 g((total + 255) / 256);
        norm_rows_kernel<<<g, 256, 0, stream>>>(anchor, support, qb, sb);
    }
    {
        dim3 g((NROWS + 63) / 64, CLASSES);
        knn_mfma_kernel<<<g, 256, 0, stream>>>(qb, sb, rowcls);
    }
    {
        dim3 g(B_ANCH * CLASSES);
        reduce_kernel<<<g, 64, 0, stream>>>(rowcls, (float*)d_out);
    }
}

// Round 4
// 63.920 us; speedup vs baseline: 5.6754x; 2.6690x over previous
//
#include <hip/hip_runtime.h>
#include <hip/hip_bf16.h>
#include <math.h>

// Problem constants (from setup_inputs / reference)
#define CLASSES     5
#define C_DIM       64
#define HW          441            // 21*21
#define B_ANCH      32
#define NSUP        25             // L*S support images
#define NROWS       (B_ANCH*HW)    // 14112 query rows
#define MSUP        (NSUP*HW)      // 11025 support descriptors
#define PER_CLS     (MSUP/CLASSES) // 2205 per class
#define TILE_COLS   128
#define NTILES      18             // ceil(2205/128) -> pad to 2304
#define PER_CLS_PAD (NTILES*TILE_COLS)      // 2304
#define NPAD        (PER_CLS_PAD - PER_CLS) // 99 zero-filled pad rows/class
#define ROW_BYTES   (C_DIM*2)      // 128 B per bf16 descriptor row

#define NEG_INF  (-1e30f)

typedef __bf16 bf16x8 __attribute__((ext_vector_type(8)));
typedef float  f32x4  __attribute__((ext_vector_type(4)));

// top-3 insert via med3: 3 independent ops; t0 >= t1 >= t2 invariant.
#define TOP3_INS(v, t0, t1, t2) do {                              \
    float _v = (v);                                               \
    float _n0 = fmaxf(_v, (t0));                                  \
    float _n1 = __builtin_amdgcn_fmed3f(_v, (t0), (t1));          \
    float _n2 = __builtin_amdgcn_fmed3f(_v, (t1), (t2));          \
    (t0) = _n0; (t1) = _n1; (t2) = _n2; } while (0)

typedef __attribute__((address_space(1))) const void g_void;
typedef __attribute__((address_space(3))) void l_void;
__device__ __forceinline__ void gload_lds16(const void* g, void* l) {
    // async global->LDS, 16 B/lane; LDS dest = uniform base + lane*16
    __builtin_amdgcn_global_load_lds((g_void*)g, (l_void*)l, 16, 0, 0);
}

// ---------------------------------------------------------------------------
// Kernel 1: L2-normalize all rows (support + anchor) into row-major bf16.
// Support goes to sb with per-class row stride PER_CLS_PAD; pad rows zeroed
// (deterministic — workspace is poisoned, pads feed masked MFMA lanes).
// ---------------------------------------------------------------------------
__global__ __launch_bounds__(256) void norm_rows_kernel(
    const float* __restrict__ anchor, const float* __restrict__ support,
    __bf16* __restrict__ qb, __bf16* __restrict__ sb) {
    int r = blockIdx.x * 256 + threadIdx.x;
    const int total_main = MSUP + NROWS;
    if (r >= total_main) {
        int i = r - total_main;                    // pad-row zero fill
        if (i < CLASSES * NPAD) {
            int cls = i / NPAD, ix = PER_CLS + i % NPAD;
            __bf16* op = sb + ((size_t)cls * PER_CLS_PAD + ix) * C_DIM;
            bf16x8 z = {};
            #pragma unroll
            for (int c0 = 0; c0 < C_DIM; c0 += 8) *(bf16x8*)(op + c0) = z;
        }
        return;
    }
    bool isSup = r < MSUP;
    int rc = isSup ? r : r - MSUP;
    const float* in = isSup ? support : anchor;
    int img = rc / HW, p = rc % HW;
    const float* base = in + (size_t)img * C_DIM * HW + p;
    float q[C_DIM];
    float ss = 0.f;
    #pragma unroll
    for (int c = 0; c < C_DIM; ++c) { q[c] = base[c * HW]; ss += q[c] * q[c]; }
    float sc = rsqrtf(ss);
    __bf16* op;
    if (isSup) {
        int cls = rc / PER_CLS, ix = rc - cls * PER_CLS;
        op = sb + ((size_t)cls * PER_CLS_PAD + ix) * C_DIM;
    } else {
        op = qb + (size_t)rc * C_DIM;
    }
    #pragma unroll
    for (int c0 = 0; c0 < C_DIM; c0 += 8) {
        bf16x8 v;
        #pragma unroll
        for (int j = 0; j < 8; ++j) v[j] = (__bf16)(q[c0 + j] * sc);
        *(bf16x8*)(op + c0) = v;
    }
}

// ---------------------------------------------------------------------------
// Kernel 2: MFMA GEMM + per-(row,class) top-3 + sigmoid.
// Grid (221, 5), block 256 = 4 waves; wave w owns 16 query rows (A in regs).
// B staged via global_load_lds into LDS in FRAGMENT-MAJOR layout (the per-lane
// global source address is pre-permuted so LDS slot [s][h][lane] holds exactly
// lane's B-frag: row s*16+(lane&15), k-half h, bytes (lane>>4)*16). ds_read is
// then uniform_base + lane*16 -> conflict-free ds_read_b128.
// Double-buffered, 1 barrier/tile; loads for tile t+1 issued at top of tile t.
// A/B frag: row/col = lane&15, k = (lane>>4)*8+[0..7].
// C/D: col = lane&15, row = (lane>>4)*4 + reg.   (validated rounds 2-3)
// ---------------------------------------------------------------------------
__global__ __launch_bounds__(256) void knn_mfma_kernel(
    const __bf16* __restrict__ qb, const __bf16* __restrict__ sb,
    float* __restrict__ rowcls /* [NROWS][CLASSES] */) {
    __shared__ bf16x8 smem[2][8][2][64];   // [buf][s][h][lane] = 32 KB

    int lane = threadIdx.x & 63;
    int w    = threadIdx.x >> 6;
    int lr   = lane & 15;      // A-row / B-col index
    int kg   = lane >> 4;      // k-group
    int cls  = blockIdx.y;
    int rowbase = blockIdx.x * 64 + w * 16;

    // A fragments (K=64 in two K=32 halves), clamped on the ragged last block
    int arow = rowbase + lr;
    int arc  = arow < NROWS ? arow : NROWS - 1;
    const bf16x8* qrow = (const bf16x8*)(qb + (size_t)arc * C_DIM);
    bf16x8 a0 = qrow[kg];
    bf16x8 a1 = qrow[4 + kg];

    float t0[4], t1[4], t2[4];
    #pragma unroll
    for (int j = 0; j < 4; ++j) { t0[j] = NEG_INF; t1[j] = NEG_INF; t2[j] = NEG_INF; }

    const char* sbCls = (const char*)sb + (size_t)cls * PER_CLS_PAD * ROW_BYTES;
    int laneOff = lr * ROW_BYTES + kg * 16;   // per-lane source permutation

    // stage tile t into LDS buffer buf: 16 (s,h) granules of 1 KB, 4 per wave
    auto stage = [&](int buf, int t) {
        const char* tbase = sbCls + (size_t)t * (TILE_COLS * ROW_BYTES);
        #pragma unroll
        for (int i = 0; i < 4; ++i) {
            int pr = w + 4 * i;
            int s = pr >> 1, h = pr & 1;
            gload_lds16(tbase + s * (16 * ROW_BYTES) + h * 64 + laneOff,
                        &smem[buf][s][h][0]);
        }
    };

    stage(0, 0);
    #pragma unroll 1
    for (int t = 0; t < NTILES; ++t) {
        __syncthreads();               // tile t staged (vmcnt+lgkm drained)
        int buf = t & 1;
        if (t + 1 < NTILES) stage((t + 1) & 1, t + 1);
        if (t < NTILES - 1) {
            #pragma unroll
            for (int s = 0; s < 8; ++s) {
                bf16x8 b0 = smem[buf][s][0][lane];
                bf16x8 b1 = smem[buf][s][1][lane];
                f32x4 acc = {0.f, 0.f, 0.f, 0.f};
                acc = __builtin_amdgcn_mfma_f32_16x16x32_bf16(a0, b0, acc, 0, 0, 0);
                acc = __builtin_amdgcn_mfma_f32_16x16x32_bf16(a1, b1, acc, 0, 0, 0);
                #pragma unroll
                for (int j = 0; j < 4; ++j) TOP3_INS(acc[j], t0[j], t1[j], t2[j]);
            }
        } else {
            // last tile: cols 2176..2303. s=0 fully valid; s=1 valid iff lr<13
            // (col 2192+lr <= 2204); s>=2 entirely pad -> skipped.
            {
                bf16x8 b0 = smem[buf][0][0][lane];
                bf16x8 b1 = smem[buf][0][1][lane];
                f32x4 acc = {0.f, 0.f, 0.f, 0.f};
                acc = __builtin_amdgcn_mfma_f32_16x16x32_bf16(a0, b0, acc, 0, 0, 0);
                acc = __builtin_amdgcn_mfma_f32_16x16x32_bf16(a1, b1, acc, 0, 0, 0);
                #pragma unroll
                for (int j = 0; j < 4; ++j) TOP3_INS(acc[j], t0[j], t1[j], t2[j]);
            }
            {
                bf16x8 b0 = smem[buf][1][0][lane];
                bf16x8 b1 = smem[buf][1][1][lane];
                f32x4 acc = {0.f, 0.f, 0.f, 0.f};
                acc = __builtin_amdgcn_mfma_f32_16x16x32_bf16(a0, b0, acc, 0, 0, 0);
                acc = __builtin_amdgcn_mfma_f32_16x16x32_bf16(a1, b1, acc, 0, 0, 0);
                bool valid = lr < 13;   // select, not add: pads stay out
                #pragma unroll
                for (int j = 0; j < 4; ++j) {
                    float v = valid ? acc[j] : NEG_INF;
                    TOP3_INS(v, t0[j], t1[j], t2[j]);
                }
            }
        }
    }

    // Merge top-3 across the 16 column-lanes per row; sigmoid; store.
    #pragma unroll
    for (int j = 0; j < 4; ++j) {
        float u0 = t0[j], u1 = t1[j], u2 = t2[j];
        #pragma unroll
        for (int off = 1; off < 16; off <<= 1) {
            float v0 = __shfl_xor(u0, off, 64);
            float v1 = __shfl_xor(u1, off, 64);
            float v2 = __shfl_xor(u2, off, 64);
            TOP3_INS(v0, u0, u1, u2);
            TOP3_INS(v1, u0, u1, u2);
            TOP3_INS(v2, u0, u1, u2);
        }
        int row = rowbase + kg * 4 + j;
        if (lr == 0 && row < NROWS) {
            float s = 1.f / (1.f + __expf(-u0))
                    + 1.f / (1.f + __expf(-u1))
                    + 1.f / (1.f + __expf(-u2));
            rowcls[(size_t)row * CLASSES + cls] = s;
        }
    }
}

// ---------------------------------------------------------------------------
// Kernel 3: reduce per-(row,class) scalars over the 441 query locations.
// ---------------------------------------------------------------------------
__global__ __launch_bounds__(64) void reduce_kernel(
    const float* __restrict__ rowcls, float* __restrict__ out) {
    int bl = blockIdx.x;
    int b = bl / CLASSES;
    int l = bl % CLASSES;
    int lane = threadIdx.x;
    float acc = 0.f;
    for (int p = lane; p < HW; p += 64)
        acc += rowcls[(size_t)(b * HW + p) * CLASSES + l];
    #pragma unroll
    for (int off = 32; off; off >>= 1) acc += __shfl_xor(acc, off, 64);
    if (lane == 0) out[bl] = acc;
}

// ---------------------------------------------------------------------------
extern "C" void kernel_launch(void* const* d_in, const int* in_sizes, int n_in,
                              void* d_out, int out_size, void* d_ws, size_t ws_size,
                              hipStream_t stream) {
    const float* anchor  = (const float*)d_in[0];
    const float* support = (const float*)d_in[1];
    // d_in[2]=av_num(1), d_in[3]=sav_num(1) -- fixed by setup, ignored.

    // ws: sb (bf16 5*2304*64) | qb (bf16 NROWS*64) | rowcls (f32 NROWS*5)
    __bf16* sb = (__bf16*)d_ws;
    __bf16* qb = sb + (size_t)CLASSES * PER_CLS_PAD * C_DIM;
    float* rowcls = (float*)(qb + (size_t)NROWS * C_DIM);

    {
        int total = MSUP + NROWS + CLASSES * NPAD;
        dim3 g((total + 255) / 256);
        norm_rows_kernel<<<g, 256, 0, stream>>>(anchor, support, qb, sb);
    }
    {
        dim3 g((NROWS + 63) / 64, CLASSES);
        knn_mfma_kernel<<<g, 256, 0, stream>>>(qb, sb, rowcls);
    }
    {
        dim3 g(B_ANCH * CLASSES);
        reduce_kernel<<<g, 64, 0, stream>>>(rowcls, (float*)d_out);
    }
}